// Round 11
// baseline (941.428 us; speedup 1.0000x reference)
//
#include <hip/hip_runtime.h>
#include <hip/hip_bf16.h>
#include <hip/hip_fp16.h>

#define RN 4096
#define EN 131072
#define TN 1536
#define T2 768            // sample-pairs per row
#define SP 1040           // padded row stride in pairs
#define PADP 257          // front wrap-replica pairs
#define PN 256
#define NBOUNCE 12
#define NCHUNK 4          // chunk c -> XCDs {c, c+4} (R4/R7 validated)
#define CP 192            // pairs per chunk = 64 lanes x 3 pairs
// np.float32(np.log(1e-3))
#define LOG_GAMMA -6.90775528f
#define INV_SR (1.0f / 16000.0f)

#define rfl(x) __builtin_amdgcn_readfirstlane(x)

// ---------------- CSR build (per-row edges split lo-col / hi-col) ----------

__global__ void hist_kernel(const int* __restrict__ row, const int* __restrict__ col,
                            int* __restrict__ cntL, int* __restrict__ cntH) {
    int e = blockIdx.x * blockDim.x + threadIdx.x;
    if (e >= EN) return;
    int r = row[e];
    if (col[e] < 2048) atomicAdd(&cntL[r], 1);
    else               atomicAdd(&cntH[r], 1);
}

// single block, 1024 threads: exclusive scan of row totals (lo edges first).
__global__ void scan_kernel(const int* __restrict__ cntL, const int* __restrict__ cntH,
                            int* __restrict__ off, int* __restrict__ curL,
                            int* __restrict__ curH) {
    __shared__ int part[1024];
    int tid = threadIdx.x;
    int l0 = cntL[tid * 4 + 0], h0 = cntH[tid * 4 + 0];
    int l1 = cntL[tid * 4 + 1], h1 = cntH[tid * 4 + 1];
    int l2 = cntL[tid * 4 + 2], h2 = cntH[tid * 4 + 2];
    int l3 = cntL[tid * 4 + 3], h3 = cntH[tid * 4 + 3];
    int n0 = l0 + h0, n1 = l1 + h1, n2 = l2 + h2, n3 = l3 + h3;
    part[tid] = n0 + n1 + n2 + n3;
    __syncthreads();
    for (int ofs = 1; ofs < 1024; ofs <<= 1) {
        int x = (tid >= ofs) ? part[tid - ofs] : 0;
        __syncthreads();
        part[tid] += x;
        __syncthreads();
    }
    int excl = (tid == 0) ? 0 : part[tid - 1];
    int o0 = excl, o1 = o0 + n0, o2 = o1 + n1, o3 = o2 + n2;
    int r0 = tid * 4;
    off[r0 + 0] = o0; curL[r0 + 0] = o0; curH[r0 + 0] = o0 + l0;
    off[r0 + 1] = o1; curL[r0 + 1] = o1; curH[r0 + 1] = o1 + l1;
    off[r0 + 2] = o2; curL[r0 + 2] = o2; curH[r0 + 2] = o2 + l2;
    off[r0 + 3] = o3; curL[r0 + 3] = o3; curH[r0 + 3] = o3 + l3;
    if (tid == 1023) off[RN] = o3 + n3;
}

// per edge: kernel value + precomputed relative byte offset into the padded layout.
// md.x = ((col*SP + PADP - dpair) << 2) | (delay & 1),  md.y = bits(kern)
__global__ void scatter_kernel(const int* __restrict__ row, const int* __restrict__ col,
                               const int* __restrict__ rid, const int* __restrict__ delay,
                               const float* __restrict__ basis,
                               const float* __restrict__ absorption,
                               const float* __restrict__ scattering,
                               int* __restrict__ curL, int* __restrict__ curH,
                               int2* __restrict__ mdarr) {
    int e = blockIdx.x * blockDim.x + threadIdx.x;
    if (e >= EN) return;
    int p = rid[e];
    float a = absorption[p];
    float s = scattering[p];
    float k = (1.0f - a) * (s * basis[e] + (1.0f - s) * basis[EN + e]);
    int d = delay[e];
    int c = col[e];
    int dpair = (d + 1) >> 1;                       // d in [0,512)
    int o = ((c * SP + PADP - dpair) << 2) | (d & 1);
    int r = row[e];
    int pos = (c < 2048) ? atomicAdd(&curL[r], 1) : atomicAdd(&curH[r], 1);
    mdarr[pos] = make_int2(o, __float_as_int(k));
}

// ---------------- init: padded cur = half(x * window) ----------------

__global__ __launch_bounds__(256) void init_kernel(const float* __restrict__ x,
                                                   __half* __restrict__ cur) {
    int r = blockIdx.x;
    int tid = threadIdx.x;
    const float* xr = x + r * TN;
    uint* curp = (uint*)cur + (size_t)r * SP;
#pragma unroll
    for (int kk = 0; kk < 3; ++kk) {
        int q = tid + kk * 256;                     // pair index
        int t = q * 2;
        float wa = __expf(LOG_GAMMA * (float)t * INV_SR);
        float wb = __expf(LOG_GAMMA * (float)(t + 1) * INV_SR);
        __half2 h = __float22half2_rn(make_float2(xr[t] * wa, xr[t + 1] * wb));
        uint u = *(uint*)&h;
        curp[PADP + q] = u;
        if (q >= 511) curp[q - 511] = u;            // wrap replica
    }
}

// ---------------- bounce: fully-resident grid, register-carried phases -------
// Grid = 2048 blocks x 128 thr (= 8 blocks/CU x 256 CU -> ALL resident, no
// dispatch stagger). Block bid: chunk = bid&3 (XCD affinity: bid%8 -> XCDs
// {chunk, chunk+4}), rgrp = bid>>2. Wave w carries FOUR row-layers
// r = rgrp*2+w+1024*L with acc[4][6] in registers, and sweeps
// phase 0 (col<2048) then phase 1 (col>=2048) over all layers. All resident
// blocks gather from the same 2048-source-row half at a time -> per-XCD
// window 2048 x 452 pairs x 4B = 3.7 MB <= 4 MB L2 (hard footprint bound,
// immune to the drift that nulled R9/R10's soft ordering).
// nxt writes are NONTEMPORAL: no write-allocate pollution of the gather
// window mid-bounce (inter-bounce L2 reuse of nxt is ~0 anyway).
// Per edge per lane: ONE global_load_dwordx4 = 3 pairs + realign dword.

#define ISSUE(W, mo)                                                   \
    {                                                                  \
        const uint* rp_ = (const uint*)(curb + (size_t)((mo) & ~1u));  \
        W = *(const uint4*)(rp_ + pb);                                 \
    }

#define CONSUME(W, mo, kb, ACC)                                        \
    {                                                                  \
        float k_ = __uint_as_float((uint)(kb));                        \
        uint v0_, v1_, v2_;                                            \
        if ((mo) & 1u) {                                               \
            v0_ = __builtin_amdgcn_alignbit(W.y, W.x, 16);             \
            v1_ = __builtin_amdgcn_alignbit(W.z, W.y, 16);             \
            v2_ = __builtin_amdgcn_alignbit(W.w, W.z, 16);             \
        } else { v0_ = W.x; v1_ = W.y; v2_ = W.z; }                    \
        __half2 h0_ = *(__half2*)&v0_;                                 \
        __half2 h1_ = *(__half2*)&v1_;                                 \
        __half2 h2_ = *(__half2*)&v2_;                                 \
        ACC[0] = fmaf(k_, __half2float(h0_.x), ACC[0]);                \
        ACC[1] = fmaf(k_, __half2float(h0_.y), ACC[1]);                \
        ACC[2] = fmaf(k_, __half2float(h1_.x), ACC[2]);                \
        ACC[3] = fmaf(k_, __half2float(h1_.y), ACC[3]);                \
        ACC[4] = fmaf(k_, __half2float(h2_.x), ACC[4]);                \
        ACC[5] = fmaf(k_, __half2float(h2_.y), ACC[5]);                \
    }

#define SEGMENT(S0, S1, ACC)                                           \
    if ((S1) > (S0)) {                                                 \
        int2 md = mdarr[S0];                                           \
        uint mo = (uint)rfl(md.x), kb = (uint)rfl(md.y);               \
        uint4 W; ISSUE(W, mo);                                         \
        for (int j = (S0) + 1; j < (S1); ++j) {                        \
            int2 mdn = mdarr[j];                                       \
            uint moN = (uint)rfl(mdn.x), kbN = (uint)rfl(mdn.y);       \
            uint4 WN; ISSUE(WN, moN);                                  \
            CONSUME(W, mo, kb, ACC);                                   \
            W = WN; mo = moN; kb = kbN;                                \
        }                                                              \
        CONSUME(W, mo, kb, ACC);                                       \
    }

__global__ __launch_bounds__(128, 4) void bounce_kernel(
        const __half* __restrict__ cur, __half* __restrict__ nxt,
        const int* __restrict__ offp, const int* __restrict__ cntL,
        const int2* __restrict__ mdarr) {
    int bid = blockIdx.x;                           // 0..2047
    int chunk = bid & 3;
    int rgrp = bid >> 2;                            // 0..511
    int wave = threadIdx.x >> 6;
    int lane = threadIdx.x & 63;
    int c0 = chunk * CP;
    int pb = c0 + lane * 3;                         // base pair (fixed all rows)
    const char* curb = (const char*)cur;

    float acc[4][6] = {};

#pragma unroll
    for (int ph = 0; ph < 2; ++ph) {
#pragma unroll
        for (int L = 0; L < 4; ++L) {
            int r = rgrp * 2 + wave + 1024 * L;
            int o0 = rfl(offp[r]);
            int o1 = rfl(offp[r + 1]);
            int lo = rfl(cntL[r]);
            int s0 = ph ? (o0 + lo) : o0;
            int s1 = ph ? o1 : (o0 + lo);
            SEGMENT(s0, s1, acc[L]);
        }
    }

#pragma unroll
    for (int L = 0; L < 4; ++L) {
        int r = rgrp * 2 + wave + 1024 * L;
        __half2 h0 = __float22half2_rn(make_float2(acc[L][0], acc[L][1]));
        __half2 h1 = __float22half2_rn(make_float2(acc[L][2], acc[L][3]));
        __half2 h2 = __float22half2_rn(make_float2(acc[L][4], acc[L][5]));
        uint u0 = *(uint*)&h0, u1 = *(uint*)&h1, u2 = *(uint*)&h2;
        uint* nxtp = (uint*)nxt + (size_t)r * SP;
        __builtin_nontemporal_store(u0, nxtp + PADP + pb);
        __builtin_nontemporal_store(u1, nxtp + PADP + pb + 1);
        __builtin_nontemporal_store(u2, nxtp + PADP + pb + 2);
        if (pb + 2 >= 511) {                        // wrap replica writes
            if (pb     >= 511) __builtin_nontemporal_store(u0, nxtp + pb - 511);
            if (pb + 1 >= 511) __builtin_nontemporal_store(u1, nxtp + pb - 510);
            __builtin_nontemporal_store(u2, nxtp + pb - 509);
        }
    }
}

// ---------------- detection (accumulated per bounce, fp32) ----------------

__global__ __launch_bounds__(128) void detect_kernel(
        const __half* __restrict__ buf, const float* __restrict__ w,
        const int* __restrict__ dd, float* __restrict__ det) {
    int cx = blockIdx.x;
    int r0 = blockIdx.y * 16;
    int tid = threadIdx.x;
    int tb = cx * 384 + tid;
    float acc0 = 0.f, acc1 = 0.f, acc2 = 0.f;
#pragma unroll 4
    for (int rr = 0; rr < 16; ++rr) {
        int r = r0 + rr;
        int d = dd[r];
        float wr = w[r];
        const __half* bufr = buf + (size_t)r * (SP * 2);
        int s0 = tb - d;           if (s0 < 0) s0 += TN;
        int s1 = tb + 128 - d;     if (s1 < 0) s1 += TN;
        int s2 = tb + 256 - d;     if (s2 < 0) s2 += TN;
        acc0 = fmaf(wr, __half2float(bufr[(PADP + (s0 >> 1)) * 2 + (s0 & 1)]), acc0);
        acc1 = fmaf(wr, __half2float(bufr[(PADP + (s1 >> 1)) * 2 + (s1 & 1)]), acc1);
        acc2 = fmaf(wr, __half2float(bufr[(PADP + (s2 >> 1)) * 2 + (s2 & 1)]), acc2);
    }
    atomicAdd(&det[tb], acc0);
    atomicAdd(&det[tb + 128], acc1);
    atomicAdd(&det[tb + 256], acc2);
}

__global__ void final_kernel(const float* __restrict__ det, float* __restrict__ out) {
    int t = blockIdx.x * 256 + threadIdx.x;
    if (t < TN) out[t] = det[t] * __expf(-LOG_GAMMA * (float)t * INV_SR);
}

// ---------------- launch ----------------

extern "C" void kernel_launch(void* const* d_in, const int* in_sizes, int n_in,
                              void* d_out, int out_size, void* d_ws, size_t ws_size,
                              hipStream_t stream) {
    const float* init_rad   = (const float*)d_in[0];
    const float* basis      = (const float*)d_in[1];
    const float* absorption = (const float*)d_in[2];
    const float* scattering = (const float*)d_in[3];
    const float* det_w      = (const float*)d_in[4];
    const int*   row        = (const int*)d_in[5];
    const int*   col        = (const int*)d_in[6];
    const int*   rid        = (const int*)d_in[7];
    const int*   delay      = (const int*)d_in[8];
    const int*   det_delay  = (const int*)d_in[9];
    float* out = (float*)d_out;

    char* ws = (char*)d_ws;
    size_t o = 0;
    auto alloc = [&](size_t bytes) {
        void* p = ws + o;
        o = (o + bytes + 255) & ~(size_t)255;
        return p;
    };
    int*    cntL   = (int*)alloc(RN * 4);
    int*    cntH   = (int*)alloc(RN * 4);
    int*    curL   = (int*)alloc(RN * 4);
    int*    curH   = (int*)alloc(RN * 4);
    int*    off    = (int*)alloc((RN + 1) * 4);
    int2*   mdarr  = (int2*)alloc((size_t)EN * 8);
    __half* bufA   = (__half*)alloc((size_t)RN * SP * 4);
    __half* bufB   = (__half*)alloc((size_t)RN * SP * 4);
    float*  det    = (float*)alloc(TN * 4);

    hipMemsetAsync(cntL, 0, RN * 4, stream);
    hipMemsetAsync(cntH, 0, RN * 4, stream);
    hipMemsetAsync(det, 0, TN * 4, stream);

    hist_kernel<<<EN / 256, 256, 0, stream>>>(row, col, cntL, cntH);
    scan_kernel<<<1, 1024, 0, stream>>>(cntL, cntH, off, curL, curH);
    scatter_kernel<<<EN / 256, 256, 0, stream>>>(row, col, rid, delay, basis,
                                                 absorption, scattering, curL, curH,
                                                 mdarr);
    init_kernel<<<RN, 256, 0, stream>>>(init_rad, bufA);

    dim3 dgrid(NCHUNK, RN / 16);
    detect_kernel<<<dgrid, 128, 0, stream>>>(bufA, det_w, det_delay, det);

    __half* cur = bufA;
    __half* nxt = bufB;
    for (int b = 0; b < NBOUNCE; ++b) {
        bounce_kernel<<<2048, 128, 0, stream>>>(cur, nxt, off, cntL, mdarr);
        detect_kernel<<<dgrid, 128, 0, stream>>>(nxt, det_w, det_delay, det);
        __half* tmp = cur; cur = nxt; nxt = tmp;
    }

    final_kernel<<<TN / 256, 256, 0, stream>>>(det, out);
}

// Round 12
// 795.458 us; speedup vs baseline: 1.1835x; 1.1835x over previous
//
#include <hip/hip_runtime.h>
#include <hip/hip_bf16.h>
#include <hip/hip_fp16.h>

#define RN 4096
#define EN 131072
#define TN 1536
#define T2 768            // sample-pairs per row
#define SP 1040           // padded row stride in pairs
#define PADP 257          // front wrap-replica pairs
#define PN 256
#define NBOUNCE 12
#define NCHUNK 4          // chunk c -> XCDs {c, c+4} (R4/R7 validated)
#define CP 192            // pairs per chunk = 64 lanes x 3 pairs
// np.float32(np.log(1e-3))
#define LOG_GAMMA -6.90775528f
#define INV_SR (1.0f / 16000.0f)

#define rfl(x) __builtin_amdgcn_readfirstlane(x)

// ---------------- CSR build (per-row edges split lo-col / hi-col) ----------

__global__ void hist_kernel(const int* __restrict__ row, const int* __restrict__ col,
                            int* __restrict__ cntL, int* __restrict__ cntH) {
    int e = blockIdx.x * blockDim.x + threadIdx.x;
    if (e >= EN) return;
    int r = row[e];
    if (col[e] < 2048) atomicAdd(&cntL[r], 1);
    else               atomicAdd(&cntH[r], 1);
}

// single block, 1024 threads: exclusive scan of row totals (lo edges first).
__global__ void scan_kernel(const int* __restrict__ cntL, const int* __restrict__ cntH,
                            int* __restrict__ off, int* __restrict__ curL,
                            int* __restrict__ curH) {
    __shared__ int part[1024];
    int tid = threadIdx.x;
    int l0 = cntL[tid * 4 + 0], h0 = cntH[tid * 4 + 0];
    int l1 = cntL[tid * 4 + 1], h1 = cntH[tid * 4 + 1];
    int l2 = cntL[tid * 4 + 2], h2 = cntH[tid * 4 + 2];
    int l3 = cntL[tid * 4 + 3], h3 = cntH[tid * 4 + 3];
    int n0 = l0 + h0, n1 = l1 + h1, n2 = l2 + h2, n3 = l3 + h3;
    part[tid] = n0 + n1 + n2 + n3;
    __syncthreads();
    for (int ofs = 1; ofs < 1024; ofs <<= 1) {
        int x = (tid >= ofs) ? part[tid - ofs] : 0;
        __syncthreads();
        part[tid] += x;
        __syncthreads();
    }
    int excl = (tid == 0) ? 0 : part[tid - 1];
    int o0 = excl, o1 = o0 + n0, o2 = o1 + n1, o3 = o2 + n2;
    int r0 = tid * 4;
    off[r0 + 0] = o0; curL[r0 + 0] = o0; curH[r0 + 0] = o0 + l0;
    off[r0 + 1] = o1; curL[r0 + 1] = o1; curH[r0 + 1] = o1 + l1;
    off[r0 + 2] = o2; curL[r0 + 2] = o2; curH[r0 + 2] = o2 + l2;
    off[r0 + 3] = o3; curL[r0 + 3] = o3; curH[r0 + 3] = o3 + l3;
    if (tid == 1023) off[RN] = o3 + n3;
}

// per edge: kernel value + precomputed relative byte offset into the padded layout.
// md.x = ((col*SP + PADP - dpair) << 2) | (delay & 1),  md.y = bits(kern)
__global__ void scatter_kernel(const int* __restrict__ row, const int* __restrict__ col,
                               const int* __restrict__ rid, const int* __restrict__ delay,
                               const float* __restrict__ basis,
                               const float* __restrict__ absorption,
                               const float* __restrict__ scattering,
                               int* __restrict__ curL, int* __restrict__ curH,
                               int2* __restrict__ mdarr) {
    int e = blockIdx.x * blockDim.x + threadIdx.x;
    if (e >= EN) return;
    int p = rid[e];
    float a = absorption[p];
    float s = scattering[p];
    float k = (1.0f - a) * (s * basis[e] + (1.0f - s) * basis[EN + e]);
    int d = delay[e];
    int c = col[e];
    int dpair = (d + 1) >> 1;                       // d in [0,512)
    int o = ((c * SP + PADP - dpair) << 2) | (d & 1);
    int r = row[e];
    int pos = (c < 2048) ? atomicAdd(&curL[r], 1) : atomicAdd(&curH[r], 1);
    mdarr[pos] = make_int2(o, __float_as_int(k));
}

// ---------------- init: padded cur = half(x * window) ----------------

__global__ __launch_bounds__(256) void init_kernel(const float* __restrict__ x,
                                                   __half* __restrict__ cur) {
    int r = blockIdx.x;
    int tid = threadIdx.x;
    const float* xr = x + r * TN;
    uint* curp = (uint*)cur + (size_t)r * SP;
#pragma unroll
    for (int kk = 0; kk < 3; ++kk) {
        int q = tid + kk * 256;                     // pair index
        int t = q * 2;
        float wa = __expf(LOG_GAMMA * (float)t * INV_SR);
        float wb = __expf(LOG_GAMMA * (float)(t + 1) * INV_SR);
        __half2 h = __float22half2_rn(make_float2(xr[t] * wa, xr[t + 1] * wb));
        uint u = *(uint*)&h;
        curp[PADP + q] = u;
        if (q >= 511) curp[q - 511] = u;            // wrap replica
    }
}

// ---------------- bounce: hard-phased + dual-stream MLP ----------------------
// Grid = 4096 blocks x 128 thr = 16 blocks/CU x 2 waves = 32 waves/CU, ALL
// resident (R11's hard phase windows: FETCH 115->51 MB) at R7's wave count
// (R11's 16 waves/CU was the 62us latency regression). Wave w of block
// (rgrp, chunk=bid&3) owns rows rA=rgrp*2+w and rB=rA+2048 and runs them as
// two INTERLEAVED depth-2 gather pipelines: while one stream's dwordx4 is
// being consumed, the other stream's load (and this stream's next) stay in
// flight -> 3-4 outstanding gathers/wave vs R11's 1-2.
// Phases: ph0 = col<2048 edges of both rows, ph1 = col>=2048 -> per-XCD
// instantaneous source window 2048 rows x 452 pairs x 4B = 3.7 MB <= 4 MB L2.
// nxt stores NONTEMPORAL (no write-allocate pollution of the gather window).

#define ISSUE(W, mo)                                                   \
    {                                                                  \
        const uint* rp_ = (const uint*)(curb + (size_t)((mo) & ~1u));  \
        W = *(const uint4*)(rp_ + pb);                                 \
    }

#define CONSUME(W, mo, kb, ACC)                                        \
    {                                                                  \
        float k_ = __uint_as_float((uint)(kb));                        \
        uint v0_, v1_, v2_;                                            \
        if ((mo) & 1u) {                                               \
            v0_ = __builtin_amdgcn_alignbit(W.y, W.x, 16);             \
            v1_ = __builtin_amdgcn_alignbit(W.z, W.y, 16);             \
            v2_ = __builtin_amdgcn_alignbit(W.w, W.z, 16);             \
        } else { v0_ = W.x; v1_ = W.y; v2_ = W.z; }                    \
        __half2 h0_ = *(__half2*)&v0_;                                 \
        __half2 h1_ = *(__half2*)&v1_;                                 \
        __half2 h2_ = *(__half2*)&v2_;                                 \
        ACC[0] = fmaf(k_, __half2float(h0_.x), ACC[0]);                \
        ACC[1] = fmaf(k_, __half2float(h0_.y), ACC[1]);                \
        ACC[2] = fmaf(k_, __half2float(h1_.x), ACC[2]);                \
        ACC[3] = fmaf(k_, __half2float(h1_.y), ACC[3]);                \
        ACC[4] = fmaf(k_, __half2float(h2_.x), ACC[4]);                \
        ACC[5] = fmaf(k_, __half2float(h2_.y), ACC[5]);                \
    }

// invariant at entry: if j<e, (mo,kb) describe edge j and W holds its data.
#define PRIME(j, e, mo, kb, W)                                         \
    if ((j) < (e)) {                                                   \
        int2 m_ = mdarr[j];                                            \
        mo = (uint)rfl(m_.x); kb = (uint)rfl(m_.y);                    \
        ISSUE(W, mo);                                                  \
    }

#define STEP(j, e, mo, kb, W, WN, ACC)                                 \
    if ((j) < (e)) {                                                   \
        int jn_ = (j) + 1;                                             \
        uint moN_ = 0, kbN_ = 0;                                       \
        if (jn_ < (e)) {                                               \
            int2 m_ = mdarr[jn_];                                      \
            moN_ = (uint)rfl(m_.x); kbN_ = (uint)rfl(m_.y);            \
            ISSUE(WN, moN_);                                           \
        }                                                              \
        CONSUME(W, mo, kb, ACC);                                       \
        W = WN; mo = moN_; kb = kbN_; j = jn_;                         \
    }

__global__ __launch_bounds__(128, 8) void bounce_kernel(
        const __half* __restrict__ cur, __half* __restrict__ nxt,
        const int* __restrict__ offp, const int* __restrict__ cntL,
        const int2* __restrict__ mdarr) {
    int bid = blockIdx.x;                           // 0..4095
    int chunk = bid & 3;
    int rgrp = bid >> 2;                            // 0..1023
    int wave = threadIdx.x >> 6;
    int lane = threadIdx.x & 63;
    int c0 = chunk * CP;
    int pb = c0 + lane * 3;                         // base pair (fixed both rows)
    const char* curb = (const char*)cur;

    int rA = rgrp * 2 + wave;
    int rB = rA + 2048;
    int oA0 = rfl(offp[rA]), oA1 = rfl(offp[rA + 1]), loA = rfl(cntL[rA]);
    int oB0 = rfl(offp[rB]), oB1 = rfl(offp[rB + 1]), loB = rfl(cntL[rB]);

    float accA[6] = {}, accB[6] = {};

#pragma unroll
    for (int ph = 0; ph < 2; ++ph) {
        int jA = ph ? (oA0 + loA) : oA0;
        int eA = ph ? oA1 : (oA0 + loA);
        int jB = ph ? (oB0 + loB) : oB0;
        int eB = ph ? oB1 : (oB0 + loB);
        uint moA = 0, kbA = 0, moB = 0, kbB = 0;
        uint4 WA = {}, WAN = {}, WB = {}, WBN = {};
        PRIME(jA, eA, moA, kbA, WA);
        PRIME(jB, eB, moB, kbB, WB);
        while (jA < eA || jB < eB) {
            STEP(jA, eA, moA, kbA, WA, WAN, accA);
            STEP(jB, eB, moB, kbB, WB, WBN, accB);
        }
    }

#pragma unroll
    for (int L = 0; L < 2; ++L) {
        int r = L ? rB : rA;
        const float* acc = L ? accB : accA;
        __half2 h0 = __float22half2_rn(make_float2(acc[0], acc[1]));
        __half2 h1 = __float22half2_rn(make_float2(acc[2], acc[3]));
        __half2 h2 = __float22half2_rn(make_float2(acc[4], acc[5]));
        uint u0 = *(uint*)&h0, u1 = *(uint*)&h1, u2 = *(uint*)&h2;
        uint* nxtp = (uint*)nxt + (size_t)r * SP;
        __builtin_nontemporal_store(u0, nxtp + PADP + pb);
        __builtin_nontemporal_store(u1, nxtp + PADP + pb + 1);
        __builtin_nontemporal_store(u2, nxtp + PADP + pb + 2);
        if (pb + 2 >= 511) {                        // wrap replica writes
            if (pb     >= 511) __builtin_nontemporal_store(u0, nxtp + pb - 511);
            if (pb + 1 >= 511) __builtin_nontemporal_store(u1, nxtp + pb - 510);
            __builtin_nontemporal_store(u2, nxtp + pb - 509);
        }
    }
}

// ---------------- detection (accumulated per bounce, fp32) ----------------

__global__ __launch_bounds__(128) void detect_kernel(
        const __half* __restrict__ buf, const float* __restrict__ w,
        const int* __restrict__ dd, float* __restrict__ det) {
    int cx = blockIdx.x;
    int r0 = blockIdx.y * 16;
    int tid = threadIdx.x;
    int tb = cx * 384 + tid;
    float acc0 = 0.f, acc1 = 0.f, acc2 = 0.f;
#pragma unroll 4
    for (int rr = 0; rr < 16; ++rr) {
        int r = r0 + rr;
        int d = dd[r];
        float wr = w[r];
        const __half* bufr = buf + (size_t)r * (SP * 2);
        int s0 = tb - d;           if (s0 < 0) s0 += TN;
        int s1 = tb + 128 - d;     if (s1 < 0) s1 += TN;
        int s2 = tb + 256 - d;     if (s2 < 0) s2 += TN;
        acc0 = fmaf(wr, __half2float(bufr[(PADP + (s0 >> 1)) * 2 + (s0 & 1)]), acc0);
        acc1 = fmaf(wr, __half2float(bufr[(PADP + (s1 >> 1)) * 2 + (s1 & 1)]), acc1);
        acc2 = fmaf(wr, __half2float(bufr[(PADP + (s2 >> 1)) * 2 + (s2 & 1)]), acc2);
    }
    atomicAdd(&det[tb], acc0);
    atomicAdd(&det[tb + 128], acc1);
    atomicAdd(&det[tb + 256], acc2);
}

__global__ void final_kernel(const float* __restrict__ det, float* __restrict__ out) {
    int t = blockIdx.x * 256 + threadIdx.x;
    if (t < TN) out[t] = det[t] * __expf(-LOG_GAMMA * (float)t * INV_SR);
}

// ---------------- launch ----------------

extern "C" void kernel_launch(void* const* d_in, const int* in_sizes, int n_in,
                              void* d_out, int out_size, void* d_ws, size_t ws_size,
                              hipStream_t stream) {
    const float* init_rad   = (const float*)d_in[0];
    const float* basis      = (const float*)d_in[1];
    const float* absorption = (const float*)d_in[2];
    const float* scattering = (const float*)d_in[3];
    const float* det_w      = (const float*)d_in[4];
    const int*   row        = (const int*)d_in[5];
    const int*   col        = (const int*)d_in[6];
    const int*   rid        = (const int*)d_in[7];
    const int*   delay      = (const int*)d_in[8];
    const int*   det_delay  = (const int*)d_in[9];
    float* out = (float*)d_out;

    char* ws = (char*)d_ws;
    size_t o = 0;
    auto alloc = [&](size_t bytes) {
        void* p = ws + o;
        o = (o + bytes + 255) & ~(size_t)255;
        return p;
    };
    int*    cntL   = (int*)alloc(RN * 4);
    int*    cntH   = (int*)alloc(RN * 4);
    int*    curL   = (int*)alloc(RN * 4);
    int*    curH   = (int*)alloc(RN * 4);
    int*    off    = (int*)alloc((RN + 1) * 4);
    int2*   mdarr  = (int2*)alloc((size_t)EN * 8);
    __half* bufA   = (__half*)alloc((size_t)RN * SP * 4);
    __half* bufB   = (__half*)alloc((size_t)RN * SP * 4);
    float*  det    = (float*)alloc(TN * 4);

    hipMemsetAsync(cntL, 0, RN * 4, stream);
    hipMemsetAsync(cntH, 0, RN * 4, stream);
    hipMemsetAsync(det, 0, TN * 4, stream);

    hist_kernel<<<EN / 256, 256, 0, stream>>>(row, col, cntL, cntH);
    scan_kernel<<<1, 1024, 0, stream>>>(cntL, cntH, off, curL, curH);
    scatter_kernel<<<EN / 256, 256, 0, stream>>>(row, col, rid, delay, basis,
                                                 absorption, scattering, curL, curH,
                                                 mdarr);
    init_kernel<<<RN, 256, 0, stream>>>(init_rad, bufA);

    dim3 dgrid(NCHUNK, RN / 16);
    detect_kernel<<<dgrid, 128, 0, stream>>>(bufA, det_w, det_delay, det);

    __half* cur = bufA;
    __half* nxt = bufB;
    for (int b = 0; b < NBOUNCE; ++b) {
        bounce_kernel<<<4096, 128, 0, stream>>>(cur, nxt, off, cntL, mdarr);
        detect_kernel<<<dgrid, 128, 0, stream>>>(nxt, det_w, det_delay, det);
        __half* tmp = cur; cur = nxt; nxt = tmp;
    }

    final_kernel<<<TN / 256, 256, 0, stream>>>(det, out);
}

// Round 14
// 529.992 us; speedup vs baseline: 1.7763x; 1.5009x over previous
//
#include <hip/hip_runtime.h>
#include <hip/hip_bf16.h>
#include <hip/hip_fp16.h>

#define RN 4096
#define EN 131072
#define TN 1536
#define SPB 2064          // padded row stride in BYTES (512 front pad + 1536 + 16 slack)
#define PADB 512          // front wrap-replica bytes (= max delay span)
#define PN 256
#define NBOUNCE 12
#define NCHUNK 4          // chunk c -> XCDs {c, c+4} (R4/R7 validated)
#define CPB 384           // samples (bytes) per chunk = 64 lanes x 6
// np.float32(np.log(1e-3))
#define LOG_GAMMA -6.90775528f
#define INV_SR (1.0f / 16000.0f)

#define rfl(x) __builtin_amdgcn_readfirstlane(x)
typedef float v2f __attribute__((ext_vector_type(2)));
typedef unsigned char uchar;

// ---------------- CSR build (per-row edges split lo-col / hi-col) ----------

__global__ void hist_kernel(const int* __restrict__ row, const int* __restrict__ col,
                            int* __restrict__ cnt2) {
    int e = blockIdx.x * blockDim.x + threadIdx.x;
    if (e < EN) atomicAdd(&cnt2[row[e] * 2 + (col[e] >> 11)], 1);
}

// single block, 1024 threads: exclusive scan of even-rounded row totals.
__global__ void scan_kernel(const int* __restrict__ cnt2, int* __restrict__ off,
                            int* __restrict__ cursor2, int* __restrict__ ntot) {
    __shared__ int part[1024];
    int tid = threadIdx.x;
    int l0 = cnt2[(tid * 4 + 0) * 2], h0 = cnt2[(tid * 4 + 0) * 2 + 1];
    int l1 = cnt2[(tid * 4 + 1) * 2], h1 = cnt2[(tid * 4 + 1) * 2 + 1];
    int l2 = cnt2[(tid * 4 + 2) * 2], h2 = cnt2[(tid * 4 + 2) * 2 + 1];
    int l3 = cnt2[(tid * 4 + 3) * 2], h3 = cnt2[(tid * 4 + 3) * 2 + 1];
    int n0 = l0 + h0, n1 = l1 + h1, n2 = l2 + h2, n3 = l3 + h3;
    int p0 = (n0 + 1) & ~1, p1 = (n1 + 1) & ~1, p2 = (n2 + 1) & ~1, p3 = (n3 + 1) & ~1;
    part[tid] = p0 + p1 + p2 + p3;
    __syncthreads();
    for (int ofs = 1; ofs < 1024; ofs <<= 1) {
        int x = (tid >= ofs) ? part[tid - ofs] : 0;
        __syncthreads();
        part[tid] += x;
        __syncthreads();
    }
    int excl = (tid == 0) ? 0 : part[tid - 1];
    int o0 = excl, o1 = o0 + p0, o2 = o1 + p1, o3 = o2 + p2;
    int r0 = tid * 4;
    off[r0 + 0] = o0; cursor2[(r0 + 0) * 2] = o0; cursor2[(r0 + 0) * 2 + 1] = o0 + l0; ntot[r0 + 0] = n0;
    off[r0 + 1] = o1; cursor2[(r0 + 1) * 2] = o1; cursor2[(r0 + 1) * 2 + 1] = o1 + l1; ntot[r0 + 1] = n1;
    off[r0 + 2] = o2; cursor2[(r0 + 2) * 2] = o2; cursor2[(r0 + 2) * 2 + 1] = o2 + l2; ntot[r0 + 2] = n2;
    off[r0 + 3] = o3; cursor2[(r0 + 3) * 2] = o3; cursor2[(r0 + 3) * 2 + 1] = o3 + l3; ntot[r0 + 3] = n3;
    if (tid == 1023) off[RN] = o3 + p3;
}

// per edge: kernel value + BYTE offset into the fp8 padded layout.
// md.x = col*SPB + PADB - delay  (byte-granular; no parity flag needed)
__global__ void scatter_kernel(const int* __restrict__ row, const int* __restrict__ col,
                               const int* __restrict__ rid, const int* __restrict__ delay,
                               const float* __restrict__ basis,
                               const float* __restrict__ absorption,
                               const float* __restrict__ scattering,
                               int* __restrict__ cursor2, int2* __restrict__ mdarr) {
    int e = blockIdx.x * blockDim.x + threadIdx.x;
    if (e >= EN) return;
    int p = rid[e];
    float a = absorption[p];
    float s = scattering[p];
    float k = (1.0f - a) * (s * basis[e] + (1.0f - s) * basis[EN + e]);
    int c = col[e];
    int o = c * SPB + PADB - delay[e];
    int pos = atomicAdd(&cursor2[row[e] * 2 + (c >> 11)], 1);
    mdarr[pos] = make_int2(o, __float_as_int(k));
}

// fill per-row pad slots (k=0, safe offset) + global tail pads
__global__ void padfill_kernel(const int* __restrict__ off, const int* __restrict__ ntot,
                               int2* __restrict__ mdarr) {
    int r = blockIdx.x * 256 + threadIdx.x;
    if (r < RN) {
        int n = ntot[r];
        if (n & 1) mdarr[off[r] + n] = make_int2(PADB, 0);
    }
    if (r < 8) mdarr[off[RN] + r] = make_int2(PADB, 0);
}

// ---------------- init: fp8 state = e4m3(x * window), front wrap replica ------

__global__ __launch_bounds__(128) void init_kernel(const float* __restrict__ x,
                                                   uchar* __restrict__ cur) {
    int r = blockIdx.x;
    int tid = threadIdx.x;
    const float* xr = x + r * TN;
    uchar* rowb = cur + (size_t)r * SPB;
#pragma unroll
    for (int kk = 0; kk < 3; ++kk) {
        int j = tid + kk * 128;                     // dword index 0..383
        int t = j * 4;
        float f0 = xr[t + 0] * __expf(LOG_GAMMA * (float)(t + 0) * INV_SR);
        float f1 = xr[t + 1] * __expf(LOG_GAMMA * (float)(t + 1) * INV_SR);
        float f2 = xr[t + 2] * __expf(LOG_GAMMA * (float)(t + 2) * INV_SR);
        float f3 = xr[t + 3] * __expf(LOG_GAMMA * (float)(t + 3) * INV_SR);
        uint u = (uint)__builtin_amdgcn_cvt_pk_fp8_f32(f0, f1, 0, false);
        u = (uint)__builtin_amdgcn_cvt_pk_fp8_f32(f2, f3, (int)u, true);
        *(uint*)(rowb + PADB + t) = u;
        if (t >= 1024) *(uint*)(rowb + t - 1024) = u;   // wrap replica (samples>=1024)
    }
}

// ---------------- bounce (R9 structure, fp8 byte-granular) --------------------
// Block = 2 waves; wave w handles row rg*2+w, chunk of 384 samples, 6/lane.
// bid = rg*4 + chunk -> chunk c on XCDs {c, c+4} (validated affinity).
// Per edge per lane: ONE aligned global_load_dwordx4 covers the 6 fp8 samples
// at any byte offset; per-lane v_alignbyte + v_cvt_pk_f32_fp8 decode.
// 2-edge A/B software pipeline, branchless even-padded CSR (validated).
// Epilogue (R13 bugfix): pack 6 fp8/lane -> LDS -> lanes 0..47 store uint2
// (48 x 8B = 384B = full chunk) + wrap replica. 8B units are 8-aligned and
// never straddle the 1024-byte replica boundary.

#define ISSUE(W, mo)                                                   \
    {                                                                  \
        uint ab_ = (uint)(mo) + (uint)pbB;                             \
        W = *(const uint4*)(curb + (ab_ & ~3u));                       \
    }

#define CONSUME(W, mo, kb)                                             \
    {                                                                  \
        float k_ = __uint_as_float((uint)(kb));                        \
        uint ab_ = (uint)(mo) + (uint)pbB;                             \
        uint sh_ = ab_ & 3u;                                           \
        uint b0_ = __builtin_amdgcn_alignbyte(W.y, W.x, sh_);          \
        uint b1_ = __builtin_amdgcn_alignbyte(W.z, W.y, sh_);          \
        v2f f01_ = __builtin_amdgcn_cvt_pk_f32_fp8((int)b0_, false);   \
        v2f f23_ = __builtin_amdgcn_cvt_pk_f32_fp8((int)b0_, true);    \
        v2f f45_ = __builtin_amdgcn_cvt_pk_f32_fp8((int)b1_, false);   \
        a0 = fmaf(k_, f01_.x, a0);                                     \
        a1 = fmaf(k_, f01_.y, a1);                                     \
        a2 = fmaf(k_, f23_.x, a2);                                     \
        a3 = fmaf(k_, f23_.y, a3);                                     \
        a4 = fmaf(k_, f45_.x, a4);                                     \
        a5 = fmaf(k_, f45_.y, a5);                                     \
    }

__global__ __launch_bounds__(128, 8) void bounce_kernel(
        const uchar* __restrict__ cur, uchar* __restrict__ nxt,
        const int* __restrict__ offp, const int* __restrict__ ntot,
        const int2* __restrict__ mdarr) {
    int bid = blockIdx.x;
    int rg = bid >> 2;
    int chunk = bid & 3;
    int wave = threadIdx.x >> 6;
    int lane = threadIdx.x & 63;
    int r = rg * 2 + wave;
    int pbB = chunk * CPB + lane * 6;               // byte base of this lane's 6 samples
    int e0 = rfl(offp[r]);
    int n  = rfl(ntot[r]);
    float a0 = 0.f, a1 = 0.f, a2 = 0.f, a3 = 0.f, a4 = 0.f, a5 = 0.f;
    const uchar* curb = cur;

    if (n > 0) {
        int e1p = e0 + ((n + 1) & ~1);
        uint4 md01 = *(const uint4*)(mdarr + e0);   // e0 even -> 16B aligned
        uint moA = (uint)rfl((int)md01.x), kbA = (uint)rfl((int)md01.y);
        uint moB = (uint)rfl((int)md01.z), kbB = (uint)rfl((int)md01.w);
        uint4 WA, WB;
        ISSUE(WA, moA);
        ISSUE(WB, moB);
        for (int j = e0 + 2; j < e1p; j += 2) {
            uint4 mdn = *(const uint4*)(mdarr + j);
            uint moC = (uint)rfl((int)mdn.x), kbC = (uint)rfl((int)mdn.y);
            uint moD = (uint)rfl((int)mdn.z), kbD = (uint)rfl((int)mdn.w);
            CONSUME(WA, moA, kbA); ISSUE(WA, moC);
            CONSUME(WB, moB, kbB); ISSUE(WB, moD);
            moA = moC; kbA = kbC; moB = moD; kbB = kbD;
        }
        CONSUME(WA, moA, kbA);
        CONSUME(WB, moB, kbB);
    }

    // pack 6 fp8 results per lane -> LDS -> 48 lanes store uint2 + replica
    __shared__ uint ldsw[256];                      // 2 waves x 512B, 16B aligned
    uchar* lds = (uchar*)ldsw;
    uint lo = (uint)__builtin_amdgcn_cvt_pk_fp8_f32(a0, a1, 0, false);
    lo = (uint)__builtin_amdgcn_cvt_pk_fp8_f32(a2, a3, (int)lo, true);
    uint hi = (uint)__builtin_amdgcn_cvt_pk_fp8_f32(a4, a5, 0, false);
    int lb = wave * 512 + lane * 6;
    *(ushort*)&lds[lb]     = (ushort)(lo & 0xffffu);
    *(ushort*)&lds[lb + 2] = (ushort)(lo >> 16);
    *(ushort*)&lds[lb + 4] = (ushort)(hi & 0xffffu);
    __syncthreads();
    if (lane < 48) {
        uint2 u = *(uint2*)&lds[wave * 512 + lane * 8];
        int sbase = chunk * CPB + lane * 8;         // byte base, 8-aligned
        uchar* rowb = nxt + (size_t)r * SPB;
        *(uint2*)(rowb + PADB + sbase) = u;
        if (sbase >= 1024) *(uint2*)(rowb + sbase - 1024) = u;  // wrap replica
    }
}

// ---------------- detection ----------------
// detect0: bounce-0 contribution straight from the fp32 INPUT (avoids fp8
// quantization of the large-magnitude initial radiance — the error budget's
// dominant term). detect: per-bounce fp8 reads; front replica kills the wrap.

__global__ __launch_bounds__(128) void detect0_kernel(
        const float* __restrict__ x, const float* __restrict__ w,
        const int* __restrict__ dd, float* __restrict__ det) {
    int cx = blockIdx.x;
    int r0 = blockIdx.y * 16;
    int tid = threadIdx.x;
    int tb = cx * 384 + tid;
    float acc0 = 0.f, acc1 = 0.f, acc2 = 0.f;
#pragma unroll 4
    for (int rr = 0; rr < 16; ++rr) {
        int r = r0 + rr;
        int d = dd[r];
        float wr = w[r];
        const float* xr = x + (size_t)r * TN;
        int s0 = tb - d;           if (s0 < 0) s0 += TN;
        int s1 = tb + 128 - d;     if (s1 < 0) s1 += TN;
        int s2 = tb + 256 - d;     if (s2 < 0) s2 += TN;
        acc0 = fmaf(wr * __expf(LOG_GAMMA * (float)s0 * INV_SR), xr[s0], acc0);
        acc1 = fmaf(wr * __expf(LOG_GAMMA * (float)s1 * INV_SR), xr[s1], acc1);
        acc2 = fmaf(wr * __expf(LOG_GAMMA * (float)s2 * INV_SR), xr[s2], acc2);
    }
    atomicAdd(&det[tb], acc0);
    atomicAdd(&det[tb + 128], acc1);
    atomicAdd(&det[tb + 256], acc2);
}

__global__ __launch_bounds__(128) void detect_kernel(
        const uchar* __restrict__ buf, const float* __restrict__ w,
        const int* __restrict__ dd, float* __restrict__ det) {
    int cx = blockIdx.x;
    int r0 = blockIdx.y * 16;
    int tid = threadIdx.x;
    int tb = cx * 384 + tid;
    float acc0 = 0.f, acc1 = 0.f, acc2 = 0.f;
#pragma unroll 4
    for (int rr = 0; rr < 16; ++rr) {
        int r = r0 + rr;
        int d = dd[r];
        float wr = w[r];
        const uchar* bufr = buf + (size_t)r * SPB;
        // tb - d in (-256, 1536); PADB + tb - d >= 257 -> replica covers wrap
        v2f v0 = __builtin_amdgcn_cvt_pk_f32_fp8((int)(uint)bufr[PADB + tb - d], false);
        v2f v1 = __builtin_amdgcn_cvt_pk_f32_fp8((int)(uint)bufr[PADB + tb + 128 - d], false);
        v2f v2 = __builtin_amdgcn_cvt_pk_f32_fp8((int)(uint)bufr[PADB + tb + 256 - d], false);
        acc0 = fmaf(wr, v0.x, acc0);
        acc1 = fmaf(wr, v1.x, acc1);
        acc2 = fmaf(wr, v2.x, acc2);
    }
    atomicAdd(&det[tb], acc0);
    atomicAdd(&det[tb + 128], acc1);
    atomicAdd(&det[tb + 256], acc2);
}

__global__ void final_kernel(const float* __restrict__ det, float* __restrict__ out) {
    int t = blockIdx.x * 256 + threadIdx.x;
    if (t < TN) out[t] = det[t] * __expf(-LOG_GAMMA * (float)t * INV_SR);
}

// ---------------- launch ----------------

extern "C" void kernel_launch(void* const* d_in, const int* in_sizes, int n_in,
                              void* d_out, int out_size, void* d_ws, size_t ws_size,
                              hipStream_t stream) {
    const float* init_rad   = (const float*)d_in[0];
    const float* basis      = (const float*)d_in[1];
    const float* absorption = (const float*)d_in[2];
    const float* scattering = (const float*)d_in[3];
    const float* det_w      = (const float*)d_in[4];
    const int*   row        = (const int*)d_in[5];
    const int*   col        = (const int*)d_in[6];
    const int*   rid        = (const int*)d_in[7];
    const int*   delay      = (const int*)d_in[8];
    const int*   det_delay  = (const int*)d_in[9];
    float* out = (float*)d_out;

    char* ws = (char*)d_ws;
    size_t o = 0;
    auto alloc = [&](size_t bytes) {
        void* p = ws + o;
        o = (o + bytes + 255) & ~(size_t)255;
        return p;
    };
    int*   cnt2    = (int*)alloc(RN * 2 * 4);
    int*   cursor2 = (int*)alloc(RN * 2 * 4);
    int*   ntot    = (int*)alloc(RN * 4);
    int*   off     = (int*)alloc((RN + 1) * 4);
    int2*  mdarr   = (int2*)alloc((size_t)(EN + RN + 8) * 8);
    uchar* bufA    = (uchar*)alloc((size_t)RN * SPB);
    uchar* bufB    = (uchar*)alloc((size_t)RN * SPB);
    float* det     = (float*)alloc(TN * 4);

    hipMemsetAsync(cnt2, 0, RN * 2 * 4, stream);
    hipMemsetAsync(det, 0, TN * 4, stream);

    hist_kernel<<<EN / 256, 256, 0, stream>>>(row, col, cnt2);
    scan_kernel<<<1, 1024, 0, stream>>>(cnt2, off, cursor2, ntot);
    scatter_kernel<<<EN / 256, 256, 0, stream>>>(row, col, rid, delay, basis,
                                                 absorption, scattering, cursor2, mdarr);
    padfill_kernel<<<RN / 256, 256, 0, stream>>>(off, ntot, mdarr);
    init_kernel<<<RN, 128, 0, stream>>>(init_rad, bufA);

    dim3 dgrid(NCHUNK, RN / 16);
    detect0_kernel<<<dgrid, 128, 0, stream>>>(init_rad, det_w, det_delay, det);

    uchar* cur = bufA;
    uchar* nxt = bufB;
    for (int b = 0; b < NBOUNCE; ++b) {
        bounce_kernel<<<(RN / 2) * NCHUNK, 128, 0, stream>>>(cur, nxt, off, ntot, mdarr);
        detect_kernel<<<dgrid, 128, 0, stream>>>(nxt, det_w, det_delay, det);
        uchar* tmp = cur; cur = nxt; nxt = tmp;
    }

    final_kernel<<<TN / 256, 256, 0, stream>>>(det, out);
}